// Round 2
// baseline (121.854 us; speedup 1.0000x reference)
//
#include <hip/hip_runtime.h>

// Selection (pos/neg thresholds, argmax ties) must match the numpy f32
// reference bit-for-bit. Disable FMA contraction so "sum - a*b" is never
// fused differently than numpy evaluates it.
#pragma clang fp contract(off)

#define GMAX 256
#define K1B 128

__device__ __forceinline__ unsigned int ordf(float f) {
    unsigned int u = __float_as_uint(f);
    return (u & 0x80000000u) ? ~u : (u | 0x80000000u);
}

// Kernel 1: per-RoI max-IoU over GTs -> pos/neg bits, emitted as per-wave
// ballot masks. No argmax here (k2 recomputes it exactly for selected RoIs).
__global__ __launch_bounds__(K1B) void iou_cls_kernel(
    const float* __restrict__ rois, const float* __restrict__ gts,
    unsigned long long* __restrict__ pmask, unsigned long long* __restrict__ nmask,
    int R, int G, int NW)
{
    const int bi = blockIdx.y;
    const int r  = blockIdx.x * K1B + threadIdx.x;

    __shared__ float4 gbox[GMAX];
    __shared__ float  garea[GMAX];

    for (int t = threadIdx.x; t < G; t += K1B) {
        const float4 g4 = *reinterpret_cast<const float4*>(gts + ((size_t)bi * G + t) * 4);
        const float s = 1.0f / 1024.0f;                 // exact (power of two)
        float a = g4.x * s, b = g4.y * s, c = g4.z * s, d = g4.w * s;
        const bool valid = (a != 0.f) || (b != 0.f) || (c != 0.f) || (d != 0.f);
        if (!valid) { a = 4.f; b = 4.f; c = 4.f; d = 4.f; }  // degenerate: inter=0
        gbox[t]  = make_float4(a, b, c, d);
        garea[t] = valid ? fmaxf(c - a, 0.f) * fmaxf(d - b, 0.f) : 0.0f;
    }
    __syncthreads();
    if (r >= R) return;

    const float4 rr = *reinterpret_cast<const float4*>(rois + ((size_t)bi * R + r) * 4);
    const bool rv = (rr.x != 0.f) || (rr.y != 0.f) || (rr.z != 0.f) || (rr.w != 0.f);
    const float ar = fmaxf(rr.z - rr.x, 0.f) * fmaxf(rr.w - rr.y, 0.f);

    float best = 0.0f;                                   // iou >= 0 always
    #pragma unroll 4
    for (int g = 0; g < G; ++g) {
        const float4 gb = gbox[g];
        const float y1 = fmaxf(rr.x, gb.x);
        const float x1 = fmaxf(rr.y, gb.y);
        const float y2 = fminf(rr.z, gb.z);
        const float x2 = fminf(rr.w, gb.w);
        const float inter = fmaxf(y2 - y1, 0.f) * fmaxf(x2 - x1, 0.f);
        const float uni   = (ar + garea[g]) - inter;     // same op order as reference
        const float iou   = inter / fmaxf(uni, 1e-7f);   // IEEE f32 divide
        best = fmaxf(best, iou);                         // fl monotone: max of fl = fl of max
    }

    const bool pos = rv && (best >= 0.5f);
    const bool neg = rv && !(best >= 0.5f) && (best >= 0.1f);

    const unsigned long long bp = __ballot(pos);
    const unsigned long long bn = __ballot(neg);
    const int w = r >> 6;                                // block base is a multiple of 64
    if ((threadIdx.x & 63) == 0 && w < NW) {
        pmask[(size_t)bi * NW + w] = bp;
        nmask[(size_t)bi * NW + w] = bn;
    }
}

// Kernel 2: per image: scan ballot masks -> first 16 pos / 64 neg indices;
// exact argmax (with reference tie semantics) for the 64 selected RoIs;
// write outputs.
__global__ __launch_bounds__(512) void select_kernel(
    const float* __restrict__ rois, const float* __restrict__ gts,
    const int* __restrict__ labels,
    const unsigned long long* __restrict__ pmask, const unsigned long long* __restrict__ nmask,
    float* __restrict__ out, int R, int G, int B, int NW)
{
    const int bi  = blockIdx.x;
    const int tid = threadIdx.x;

    __shared__ int sp[512], sn[512];
    __shared__ float4 sgt[GMAX];
    __shared__ float  sgv[GMAX];
    __shared__ int plist[16], nlist[64];
    __shared__ int sridx[64];
    __shared__ unsigned long long skey[64];

    // stage normalized gts + validity
    for (int t = tid; t < G; t += 512) {
        const float4 g4 = *reinterpret_cast<const float4*>(gts + ((size_t)bi * G + t) * 4);
        const float s = 1.0f / 1024.0f;
        const float a = g4.x * s, b = g4.y * s, c = g4.z * s, d = g4.w * s;
        sgt[t] = make_float4(a, b, c, d);
        sgv[t] = ((a != 0.f) || (b != 0.f) || (c != 0.f) || (d != 0.f)) ? 1.0f : 0.0f;
    }

    unsigned long long mp = 0ull, mn = 0ull;
    if (tid < NW) {
        mp = pmask[(size_t)bi * NW + tid];
        mn = nmask[(size_t)bi * NW + tid];
    }
    const int cp = __popcll(mp);
    const int cn = __popcll(mn);
    sp[tid] = cp; sn[tid] = cn;
    if (tid < 16) plist[tid] = 0;
    if (tid < 64) nlist[tid] = 0;
    __syncthreads();
    // Hillis-Steele inclusive scan over 512
    for (int off = 1; off < 512; off <<= 1) {
        const int vp = (tid >= off) ? sp[tid - off] : 0;
        const int vn = (tid >= off) ? sn[tid - off] : 0;
        __syncthreads();
        sp[tid] += vp; sn[tid] += vn;
        __syncthreads();
    }
    const int basep = sp[tid] - cp;
    const int basen = sn[tid] - cn;

    // extract ordered indices (ascending roi index = reference's top_k trick)
    if (mp && basep < 16) {
        int rank = basep; unsigned long long m = mp;
        while (m && rank < 16) { const int b = __ffsll(m) - 1; plist[rank++] = tid * 64 + b; m &= m - 1; }
    }
    if (mn && basen < 64) {
        int rank = basen; unsigned long long m = mn;
        while (m && rank < 64) { const int b = __ffsll(m) - 1; nlist[rank++] = tid * 64 + b; m &= m - 1; }
    }
    __syncthreads();

    const int tot_p = sp[511];
    const int tot_n = sn[511];
    const int n_pos = min(tot_p, 16);
    const int n_neg = min(tot_n, 64 - n_pos);

    if (tid < 64) {
        const int slot = tid;
        const bool isp = slot < n_pos;
        const bool isn = (!isp) && (slot < n_pos + n_neg);
        sridx[slot] = isp ? plist[slot] : (isn ? nlist[slot - n_pos] : 0);
        skey[slot]  = 0ull;
    }
    __syncthreads();

    // exact argmax for each selected roi: 8 threads/slot, 32 gts each
    {
        const int slot = tid >> 3;
        const int sub  = tid & 7;
        const int ridx = sridx[slot];
        const float4 rr = *reinterpret_cast<const float4*>(rois + ((size_t)bi * R + ridx) * 4);
        const float ar = fmaxf(rr.z - rr.x, 0.f) * fmaxf(rr.w - rr.y, 0.f);
        float best = -1.0f;
        int bidx = sub * 32;
        for (int j = 0; j < 32; ++j) {
            const int g = sub * 32 + j;
            if (g >= G) break;
            const float4 gb = sgt[g];
            const float y1 = fmaxf(rr.x, gb.x);
            const float x1 = fmaxf(rr.y, gb.y);
            const float y2 = fminf(rr.z, gb.z);
            const float x2 = fminf(rr.w, gb.w);
            const float inter = fmaxf(y2 - y1, 0.f) * fmaxf(x2 - x1, 0.f);
            const float ga = fmaxf(gb.z - gb.x, 0.f) * fmaxf(gb.w - gb.y, 0.f);
            const float uni = (ar + ga) - inter;
            float v = inter / fmaxf(uni, 1e-7f);
            if (sgv[g] == 0.0f) v = -1.0f;               // reference: invalid -> -1
            if (v > best) { best = v; bidx = g; }        // strict > = first occurrence
        }
        // merge partials: larger float wins, lower g wins ties
        const unsigned long long key =
            ((unsigned long long)ordf(best) << 32) | (unsigned int)(~(unsigned int)bidx);
        atomicMax(&skey[slot], key);
    }
    __syncthreads();

    if (tid < 64) {
        const int slot = tid;
        const bool isp = slot < n_pos;
        const bool isn = (!isp) && (slot < n_pos + n_neg);
        const int ridx = sridx[slot];
        const int gidx = (int)(~(unsigned int)(skey[slot] & 0xFFFFFFFFull));

        const float4 rr = *reinterpret_cast<const float4*>(rois + ((size_t)bi * R + ridx) * 4);
        const float4 gb = sgt[gidx];
        const float vf = (isp || isn) ? 1.0f : 0.0f;
        const float eps = 1e-7f;

        const float rh  = fmaxf(rr.z - rr.x, eps);
        const float rw  = fmaxf(rr.w - rr.y, eps);
        const float rcy = rr.x + 0.5f * rh;
        const float rcx = rr.y + 0.5f * rw;
        const float gh  = fmaxf(gb.z - gb.x, eps);
        const float gw  = fmaxf(gb.w - gb.y, eps);
        const float gcy = gb.x + 0.5f * gh;
        const float gcx = gb.y + 0.5f * gw;

        float o0 = (gcy - rcy) / rh;
        float o1 = (gcx - rcx) / rw;
        float o2 = logf(gh / rh);
        float o3 = logf(gw / rw);
        o0 = (o0 * vf) / 0.1f;
        o1 = (o1 * vf) / 0.1f;
        o2 = (o2 * vf) / 0.2f;
        o3 = (o3 * vf) / 0.2f;

        const int base = bi * 64 + slot;
        reinterpret_cast<float4*>(out)[base] = make_float4(rr.x * vf, rr.y * vf, rr.z * vf, rr.w * vf);
        reinterpret_cast<float4*>(out + (size_t)B * 256)[base] = make_float4(o0, o1, o2, o3);
        out[(size_t)B * 512 + base] = isp ? (float)labels[(size_t)bi * G + gidx] : 0.0f;
    }
}

extern "C" void kernel_launch(void* const* d_in, const int* in_sizes, int n_in,
                              void* d_out, int out_size, void* d_ws, size_t ws_size,
                              hipStream_t stream)
{
    const float* rois   = (const float*)d_in[0];
    const float* gts    = (const float*)d_in[1];
    const int*   labels = (const int*)d_in[2];
    float* out = (float*)d_out;

    const int B = out_size / 576;            // 64*4 + 64*4 + 64 per image
    const int G = in_sizes[2] / B;
    const int R = in_sizes[0] / (4 * B);
    const int NW = (R + 63) / 64;

    unsigned long long* pmask = (unsigned long long*)d_ws;
    unsigned long long* nmask = pmask + (size_t)B * NW;

    dim3 gridA((R + K1B - 1) / K1B, B);
    iou_cls_kernel<<<gridA, K1B, 0, stream>>>(rois, gts, pmask, nmask, R, G, NW);
    select_kernel<<<B, 512, 0, stream>>>(rois, gts, labels, pmask, nmask, out, R, G, B, NW);
}

// Round 3
// 97.851 us; speedup vs baseline: 1.2453x; 1.2453x over previous
//
#include <hip/hip_runtime.h>

// Selection (pos/neg thresholds, argmax ties) must match the numpy f32
// reference bit-for-bit. Disable FMA contraction so "sum - a*b" is never
// fused differently than numpy evaluates it.
#pragma clang fp contract(off)

#define GMAX 256

__device__ __forceinline__ unsigned int ordf(float f) {
    unsigned int u = __float_as_uint(f);
    return (u & 0x80000000u) ? ~u : (u | 0x80000000u);
}

// Kernel 1: block = 256 threads = 4 waves; block handles 64 RoIs; wave w
// covers gts [64w, 64w+64). Exact threshold predicates in double replace the
// IEEE f32 divide:
//   fl32(a/b) >= 0.5f  <=>  a >= C1*b   (C1 = (2^25-1)/2^26, tie->even->0.5)
//   fl32(a/b) >= 0.1f  <=>  a >  C2*b   (C2 = 26843545/2^28, tie->even->pred)
// C*(double)b is a 25x24-bit product => exact in double => predicates exact.
__global__ __launch_bounds__(256) void iou_cls_kernel(
    const float* __restrict__ rois, const float* __restrict__ gts,
    unsigned long long* __restrict__ pmask, unsigned long long* __restrict__ nmask,
    int R, int G, int NW)
{
    const int bi    = blockIdx.y;
    const int lane  = threadIdx.x & 63;
    const int gbase = threadIdx.x & 192;          // (tid>>6)<<6 = wave * 64
    const int r     = blockIdx.x * 64 + lane;

    __shared__ float4 gbox[GMAX];
    __shared__ float  garea[GMAX];
    __shared__ unsigned long long bp[4], ba[4];

    // stage all gts (pad invalid / absent with degenerate far box: inter=0)
    for (int t = threadIdx.x; t < GMAX; t += 256) {
        float a = 4.f, b = 4.f, c = 4.f, d = 4.f, area = 0.f;
        if (t < G) {
            const float4 g4 = *reinterpret_cast<const float4*>(gts + ((size_t)bi * G + t) * 4);
            const float s = 1.0f / 1024.0f;       // exact (power of two)
            const float na = g4.x * s, nb = g4.y * s, nc = g4.z * s, nd = g4.w * s;
            if ((na != 0.f) || (nb != 0.f) || (nc != 0.f) || (nd != 0.f)) {
                a = na; b = nb; c = nc; d = nd;
                area = fmaxf(nc - na, 0.f) * fmaxf(nd - nb, 0.f);
            }
        }
        gbox[t]  = make_float4(a, b, c, d);
        garea[t] = area;
    }
    __syncthreads();

    float4 rr = make_float4(0.f, 0.f, 0.f, 0.f);
    if (r < R) rr = *reinterpret_cast<const float4*>(rois + ((size_t)bi * R + r) * 4);
    const bool rv = (r < R) &&
        ((rr.x != 0.f) || (rr.y != 0.f) || (rr.z != 0.f) || (rr.w != 0.f));
    const float ar = fmaxf(rr.z - rr.x, 0.f) * fmaxf(rr.w - rr.y, 0.f);

    const double C1 = 33554431.0 / 67108864.0;    // 0.5  - 2^-26 (exact)
    const double C2 = 26843545.0 / 268435456.0;   // 0.1f - 2^-28 (exact)
    bool anyp = false, any1 = false;

    #pragma unroll 4
    for (int j = 0; j < 64; ++j) {
        const int g = gbase + j;                  // wave-uniform -> LDS broadcast
        const float4 gb = gbox[g];
        const float y1 = fmaxf(rr.x, gb.x);
        const float x1 = fmaxf(rr.y, gb.y);
        const float y2 = fminf(rr.z, gb.z);
        const float x2 = fminf(rr.w, gb.w);
        const float inter = fmaxf(y2 - y1, 0.f) * fmaxf(x2 - x1, 0.f);
        const float uni   = (ar + garea[g]) - inter;   // same op order as reference
        const float uni2  = fmaxf(uni, 1e-7f);
        const double A = (double)inter;
        const double B = (double)uni2;
        anyp = anyp | (A >= C1 * B);
        any1 = any1 | (A >  C2 * B);
    }

    const int wave = threadIdx.x >> 6;
    const unsigned long long brv = __ballot(rv);  // identical in every wave
    bp[wave] = __ballot(anyp);
    ba[wave] = __ballot(any1);
    __syncthreads();

    if (threadIdx.x == 0) {
        const unsigned long long por = bp[0] | bp[1] | bp[2] | bp[3];
        const unsigned long long aor = ba[0] | ba[1] | ba[2] | ba[3];
        pmask[(size_t)bi * NW + blockIdx.x] = brv & por;
        nmask[(size_t)bi * NW + blockIdx.x] = brv & aor & ~por;
    }
}

// Kernel 2: per image: scan ballot masks -> first 16 pos / 64 neg indices;
// exact argmax (divide-based, reference tie semantics) for the 64 selected
// RoIs; write outputs. (Unchanged from the passing round-2 version.)
__global__ __launch_bounds__(512) void select_kernel(
    const float* __restrict__ rois, const float* __restrict__ gts,
    const int* __restrict__ labels,
    const unsigned long long* __restrict__ pmask, const unsigned long long* __restrict__ nmask,
    float* __restrict__ out, int R, int G, int B, int NW)
{
    const int bi  = blockIdx.x;
    const int tid = threadIdx.x;

    __shared__ int sp[512], sn[512];
    __shared__ float4 sgt[GMAX];
    __shared__ float  sgv[GMAX];
    __shared__ int plist[16], nlist[64];
    __shared__ int sridx[64];
    __shared__ unsigned long long skey[64];

    for (int t = tid; t < G; t += 512) {
        const float4 g4 = *reinterpret_cast<const float4*>(gts + ((size_t)bi * G + t) * 4);
        const float s = 1.0f / 1024.0f;
        const float a = g4.x * s, b = g4.y * s, c = g4.z * s, d = g4.w * s;
        sgt[t] = make_float4(a, b, c, d);
        sgv[t] = ((a != 0.f) || (b != 0.f) || (c != 0.f) || (d != 0.f)) ? 1.0f : 0.0f;
    }

    unsigned long long mp = 0ull, mn = 0ull;
    if (tid < NW) {
        mp = pmask[(size_t)bi * NW + tid];
        mn = nmask[(size_t)bi * NW + tid];
    }
    const int cp = __popcll(mp);
    const int cn = __popcll(mn);
    sp[tid] = cp; sn[tid] = cn;
    if (tid < 16) plist[tid] = 0;
    if (tid < 64) nlist[tid] = 0;
    __syncthreads();
    for (int off = 1; off < 512; off <<= 1) {
        const int vp = (tid >= off) ? sp[tid - off] : 0;
        const int vn = (tid >= off) ? sn[tid - off] : 0;
        __syncthreads();
        sp[tid] += vp; sn[tid] += vn;
        __syncthreads();
    }
    const int basep = sp[tid] - cp;
    const int basen = sn[tid] - cn;

    if (mp && basep < 16) {
        int rank = basep; unsigned long long m = mp;
        while (m && rank < 16) { const int b = __ffsll(m) - 1; plist[rank++] = tid * 64 + b; m &= m - 1; }
    }
    if (mn && basen < 64) {
        int rank = basen; unsigned long long m = mn;
        while (m && rank < 64) { const int b = __ffsll(m) - 1; nlist[rank++] = tid * 64 + b; m &= m - 1; }
    }
    __syncthreads();

    const int tot_p = sp[511];
    const int tot_n = sn[511];
    const int n_pos = min(tot_p, 16);
    const int n_neg = min(tot_n, 64 - n_pos);

    if (tid < 64) {
        const int slot = tid;
        const bool isp = slot < n_pos;
        const bool isn = (!isp) && (slot < n_pos + n_neg);
        sridx[slot] = isp ? plist[slot] : (isn ? nlist[slot - n_pos] : 0);
        skey[slot]  = 0ull;
    }
    __syncthreads();

    {
        const int slot = tid >> 3;
        const int sub  = tid & 7;
        const int ridx = sridx[slot];
        const float4 rr = *reinterpret_cast<const float4*>(rois + ((size_t)bi * R + ridx) * 4);
        const float ar = fmaxf(rr.z - rr.x, 0.f) * fmaxf(rr.w - rr.y, 0.f);
        float best = -1.0f;
        int bidx = sub * 32;
        for (int j = 0; j < 32; ++j) {
            const int g = sub * 32 + j;
            if (g >= G) break;
            const float4 gb = sgt[g];
            const float y1 = fmaxf(rr.x, gb.x);
            const float x1 = fmaxf(rr.y, gb.y);
            const float y2 = fminf(rr.z, gb.z);
            const float x2 = fminf(rr.w, gb.w);
            const float inter = fmaxf(y2 - y1, 0.f) * fmaxf(x2 - x1, 0.f);
            const float ga = fmaxf(gb.z - gb.x, 0.f) * fmaxf(gb.w - gb.y, 0.f);
            const float uni = (ar + ga) - inter;
            float v = inter / fmaxf(uni, 1e-7f);
            if (sgv[g] == 0.0f) v = -1.0f;
            if (v > best) { best = v; bidx = g; }        // strict > = first occurrence
        }
        const unsigned long long key =
            ((unsigned long long)ordf(best) << 32) | (unsigned int)(~(unsigned int)bidx);
        atomicMax(&skey[slot], key);
    }
    __syncthreads();

    if (tid < 64) {
        const int slot = tid;
        const bool isp = slot < n_pos;
        const bool isn = (!isp) && (slot < n_pos + n_neg);
        const int ridx = sridx[slot];
        const int gidx = (int)(~(unsigned int)(skey[slot] & 0xFFFFFFFFull));

        const float4 rr = *reinterpret_cast<const float4*>(rois + ((size_t)bi * R + ridx) * 4);
        const float4 gb = sgt[gidx];
        const float vf = (isp || isn) ? 1.0f : 0.0f;
        const float eps = 1e-7f;

        const float rh  = fmaxf(rr.z - rr.x, eps);
        const float rw  = fmaxf(rr.w - rr.y, eps);
        const float rcy = rr.x + 0.5f * rh;
        const float rcx = rr.y + 0.5f * rw;
        const float gh  = fmaxf(gb.z - gb.x, eps);
        const float gw  = fmaxf(gb.w - gb.y, eps);
        const float gcy = gb.x + 0.5f * gh;
        const float gcx = gb.y + 0.5f * gw;

        float o0 = (gcy - rcy) / rh;
        float o1 = (gcx - rcx) / rw;
        float o2 = logf(gh / rh);
        float o3 = logf(gw / rw);
        o0 = (o0 * vf) / 0.1f;
        o1 = (o1 * vf) / 0.1f;
        o2 = (o2 * vf) / 0.2f;
        o3 = (o3 * vf) / 0.2f;

        const int base = bi * 64 + slot;
        reinterpret_cast<float4*>(out)[base] = make_float4(rr.x * vf, rr.y * vf, rr.z * vf, rr.w * vf);
        reinterpret_cast<float4*>(out + (size_t)B * 256)[base] = make_float4(o0, o1, o2, o3);
        out[(size_t)B * 512 + base] = isp ? (float)labels[(size_t)bi * G + gidx] : 0.0f;
    }
}

extern "C" void kernel_launch(void* const* d_in, const int* in_sizes, int n_in,
                              void* d_out, int out_size, void* d_ws, size_t ws_size,
                              hipStream_t stream)
{
    const float* rois   = (const float*)d_in[0];
    const float* gts    = (const float*)d_in[1];
    const int*   labels = (const int*)d_in[2];
    float* out = (float*)d_out;

    const int B = out_size / 576;            // 64*4 + 64*4 + 64 per image
    const int G = in_sizes[2] / B;
    const int R = in_sizes[0] / (4 * B);
    const int NW = (R + 63) / 64;            // one mask word per 64 RoIs

    unsigned long long* pmask = (unsigned long long*)d_ws;
    unsigned long long* nmask = pmask + (size_t)B * NW;

    dim3 gridA(NW, B);                       // block handles 64 RoIs
    iou_cls_kernel<<<gridA, 256, 0, stream>>>(rois, gts, pmask, nmask, R, G, NW);
    select_kernel<<<B, 512, 0, stream>>>(rois, gts, labels, pmask, nmask, out, R, G, B, NW);
}